// Round 1
// baseline (173.873 us; speedup 1.0000x reference)
//
#include <hip/hip_runtime.h>
#include <math.h>

// SSIM on MI355X. Separable 7x7 Gaussian: 5 depthwise convs (X, Y, X^2, Y^2, XY)
// done as horizontal + vertical 1D 7-tap passes, fused with the SSIM map and a
// global mean reduction. One atomicAdd(double) per block into d_ws.

#define TW 64          // tile width (output)
#define TH 16          // tile height (output)
#define HALO 3
#define LW (TW + 2*HALO)   // 70
#define LH (TH + 2*HALO)   // 22
#define W_IMG 320
#define H_IMG 320
#define NIMG 64
#define NPIX ((double)NIMG * W_IMG * H_IMG)

struct W7 { float w[7]; };

__global__ __launch_bounds__(256) void ssim_kernel(
    const float* __restrict__ X, const float* __restrict__ Y,
    W7 wv, double* __restrict__ acc)
{
    __shared__ float sX[LH][LW];
    __shared__ float sY[LH][LW];
    __shared__ float h0[LH][TW];   // conv_h(X)
    __shared__ float h1[LH][TW];   // conv_h(Y)
    __shared__ float h2[LH][TW];   // conv_h(X*X)
    __shared__ float h3[LH][TW];   // conv_h(Y*Y)
    __shared__ float h4[LH][TW];   // conv_h(X*Y)
    __shared__ float wsum[4];

    const int tid = threadIdx.x;
    const int n   = blockIdx.z;
    const int tx0 = blockIdx.x * TW;
    const int ty0 = blockIdx.y * TH;
    const float* __restrict__ Xn = X + (size_t)n * (W_IMG * H_IMG);
    const float* __restrict__ Yn = Y + (size_t)n * (W_IMG * H_IMG);

    // ---- stage 0: global -> LDS (haloed tile, zero padding at borders) ----
    for (int i = tid; i < LH * LW; i += 256) {
        int r = i / LW;
        int c = i - r * LW;
        int gy = ty0 - HALO + r;
        int gx = tx0 - HALO + c;
        float xv = 0.f, yv = 0.f;
        if (gx >= 0 && gx < W_IMG && gy >= 0 && gy < H_IMG) {
            int idx = gy * W_IMG + gx;
            xv = Xn[idx];
            yv = Yn[idx];
        }
        sX[r][c] = xv;
        sY[r][c] = yv;
    }
    __syncthreads();

    // ---- stage 1: horizontal 7-tap on 5 channels ----
    for (int i = tid; i < LH * TW; i += 256) {
        int r = i >> 6;          // TW == 64
        int c = i & 63;
        float ax = 0.f, ay = 0.f, axx = 0.f, ayy = 0.f, axy = 0.f;
#pragma unroll
        for (int d = 0; d < 7; ++d) {
            float w  = wv.w[d];
            float xv = sX[r][c + d];
            float yv = sY[r][c + d];
            ax  += w * xv;
            ay  += w * yv;
            axx += w * xv * xv;
            ayy += w * yv * yv;
            axy += w * xv * yv;
        }
        h0[r][c] = ax;  h1[r][c] = ay;
        h2[r][c] = axx; h3[r][c] = ayy; h4[r][c] = axy;
    }
    __syncthreads();

    // ---- stage 2: vertical 7-tap + SSIM map + local accumulate ----
    const float C1   = 0.0004f;          // (0.01*2)^2
    const float C2   = 0.0036f;          // (0.03*2)^2
    const float COVN = 49.0f / 48.0f;    // NP/(NP-1)

    float lsum = 0.f;
#pragma unroll
    for (int k = 0; k < 4; ++k) {
        int p = tid + k * 256;           // 1024 pixels / 256 threads
        int y = p >> 6;
        int x = p & 63;
        float mx = 0.f, my = 0.f, sxx = 0.f, syy = 0.f, sxy = 0.f;
#pragma unroll
        for (int d = 0; d < 7; ++d) {
            float w = wv.w[d];
            mx  += w * h0[y + d][x];
            my  += w * h1[y + d][x];
            sxx += w * h2[y + d][x];
            syy += w * h3[y + d][x];
            sxy += w * h4[y + d][x];
        }
        float mxsq = mx * mx;
        float mysq = my * my;
        float mxy  = mx * my;
        float vx   = (sxx - mxsq) * COVN;
        float vy   = (syy - mysq) * COVN;
        float vxy  = (sxy - mxy)  * COVN;
        float num  = (2.f * mxy + C1) * (2.f * vxy + C2);
        float den  = (mxsq + mysq + C1) * (vx + vy + C2);
        lsum += num / den;
    }

    // ---- block reduction: wave shuffle (width 64) -> LDS -> one atomic ----
#pragma unroll
    for (int off = 32; off > 0; off >>= 1)
        lsum += __shfl_down(lsum, off, 64);
    if ((tid & 63) == 0) wsum[tid >> 6] = lsum;
    __syncthreads();
    if (tid == 0) {
        float b = wsum[0] + wsum[1] + wsum[2] + wsum[3];
        atomicAdd(acc, (double)b);
    }
}

__global__ void ssim_finalize(const double* __restrict__ acc,
                              float* __restrict__ out)
{
    out[0] = (float)(1.0 - acc[0] / NPIX);
}

extern "C" void kernel_launch(void* const* d_in, const int* in_sizes, int n_in,
                              void* d_out, int out_size, void* d_ws, size_t ws_size,
                              hipStream_t stream) {
    const float* X = (const float*)d_in[0];
    const float* Y = (const float*)d_in[1];
    // d_in[2] is the 7x7 window; it is an outer product of a 1D Gaussian, so we
    // rebuild the exact 1D weights on host in fp64 (matches numpy's computation).
    W7 wv;
    {
        double g[7], s = 0.0;
        for (int i = 0; i < 7; ++i) {
            double x = (double)(i - 3);
            g[i] = exp(-(x * x) / (2.0 * 1.5 * 1.5));
            s += g[i];
        }
        for (int i = 0; i < 7; ++i) wv.w[i] = (float)(g[i] / s);
    }

    double* acc = (double*)d_ws;
    hipMemsetAsync(acc, 0, sizeof(double), stream);

    dim3 grid(W_IMG / TW, H_IMG / TH, NIMG);   // 5 x 20 x 64 = 6400 blocks
    ssim_kernel<<<grid, 256, 0, stream>>>(X, Y, wv, acc);
    ssim_finalize<<<1, 1, 0, stream>>>(acc, (float*)d_out);
}

// Round 2
// 122.110 us; speedup vs baseline: 1.4239x; 1.4239x over previous
//
#include <hip/hip_runtime.h>
#include <math.h>

// SSIM on MI355X, round 2: separable 7x7 Gaussian, register micro-tiles,
// b128 LDS ops, LDS union (h overwrites staging), per-block partials (no atomic).

#define TW 64
#define TH 16
#define LW 72            // staging row stride (70 used, padded to 16B multiple)
#define LH 22            // TH + 6
#define WI 320
#define HI 320
#define NI 64
#define NBLK (5 * 20 * NI)           // 6400 blocks
#define NPIX ((double)NI * WI * HI)

typedef float v4 __attribute__((ext_vector_type(4)));

struct W7 { float w[7]; };

__global__ __launch_bounds__(256) void ssim_kernel(
    const float* __restrict__ X, const float* __restrict__ Y,
    W7 wv, float* __restrict__ partial)
{
    // union: first 2*LH*LW floats = staging sX,sY; after barrier reused as
    // h[5][LH][64] horizontal conv results. 5*22*64*4 = 28160 B.
    __shared__ __align__(16) float buf[5 * LH * 64];
    __shared__ float wsum[4];

    float* sX = buf;               // LH*LW = 1584 floats
    float* sY = buf + LH * LW;     // base byte offset 6336, 16B-aligned

    const int tid = threadIdx.x;
    const int tx0 = blockIdx.x * TW;
    const int ty0 = blockIdx.y * TH;
    const int n   = blockIdx.z;
    const float* __restrict__ Xn = X + (size_t)n * (WI * HI);
    const float* __restrict__ Yn = Y + (size_t)n * (WI * HI);

    // ---- stage 0: global -> LDS staging (haloed tile, zero pad at borders) ----
    for (int i = tid; i < LH * LW; i += 256) {
        int r  = i / LW;
        int c  = i - r * LW;
        int gy = ty0 - 3 + r;
        int gx = tx0 - 3 + c;
        float xv = 0.f, yv = 0.f;
        if (c < 70 && (unsigned)gy < (unsigned)HI && (unsigned)gx < (unsigned)WI) {
            int idx = gy * WI + gx;
            xv = Xn[idx];
            yv = Yn[idx];
        }
        sX[i] = xv;
        sY[i] = yv;
    }
    __syncthreads();

    // ---- stage 1: horizontal 7-tap, 4 outputs/thread, results to registers ----
    // h-points: LH*TW = 1408 = 352 groups of 4. iter0: g=tid (256), iter1: g=256+tid (96).
    float hreg[2][5][4];
#pragma unroll
    for (int it = 0; it < 2; ++it) {
        int g = tid + it * 256;
        if (g < 352) {
            int r  = g >> 4;
            int c0 = (g & 15) << 2;
            const v4* px = (const v4*)&sX[r * LW + c0];   // (r*72+c0)*4 bytes, 16B-aligned
            const v4* py = (const v4*)&sY[r * LW + c0];
            v4 xa = px[0], xb = px[1], xc = px[2];        // cols c0..c0+11 (last 2 unused)
            v4 ya = py[0], yb = py[1], yc = py[2];
            float xv[12] = {xa.x,xa.y,xa.z,xa.w, xb.x,xb.y,xb.z,xb.w, xc.x,xc.y,xc.z,xc.w};
            float yv[12] = {ya.x,ya.y,ya.z,ya.w, yb.x,yb.y,yb.z,yb.w, yc.x,yc.y,yc.z,yc.w};
            float xx[12], yy[12], xy[12];
#pragma unroll
            for (int e = 0; e < 12; ++e) {
                xx[e] = xv[e] * xv[e];
                yy[e] = yv[e] * yv[e];
                xy[e] = xv[e] * yv[e];
            }
#pragma unroll
            for (int j = 0; j < 4; ++j) {
                float ax = 0.f, ay = 0.f, axx = 0.f, ayy = 0.f, axy = 0.f;
#pragma unroll
                for (int d = 0; d < 7; ++d) {
                    float w = wv.w[d];
                    ax  += w * xv[j + d];
                    ay  += w * yv[j + d];
                    axx += w * xx[j + d];
                    ayy += w * yy[j + d];
                    axy += w * xy[j + d];
                }
                hreg[it][0][j] = ax;  hreg[it][1][j] = ay;
                hreg[it][2][j] = axx; hreg[it][3][j] = ayy; hreg[it][4][j] = axy;
            }
        }
    }
    __syncthreads();   // all staging reads done; safe to overwrite buf with h

    // ---- write h[5][LH][64] over the staging space ----
#pragma unroll
    for (int it = 0; it < 2; ++it) {
        int g = tid + it * 256;
        if (g < 352) {
            int r  = g >> 4;
            int c0 = (g & 15) << 2;
#pragma unroll
            for (int ch = 0; ch < 5; ++ch) {
                v4 t = { hreg[it][ch][0], hreg[it][ch][1],
                         hreg[it][ch][2], hreg[it][ch][3] };
                *(v4*)&buf[ch * (LH * 64) + r * 64 + c0] = t;
            }
        }
    }
    __syncthreads();

    // ---- stage 2: vertical 7-tap + SSIM, 1x4 strip per thread ----
    {
        int r  = tid >> 4;           // output row 0..15
        int c0 = (tid & 15) << 2;    // output col group
        v4 mx  = {0.f,0.f,0.f,0.f}, my  = {0.f,0.f,0.f,0.f};
        v4 sxx = {0.f,0.f,0.f,0.f}, syy = {0.f,0.f,0.f,0.f}, sxy = {0.f,0.f,0.f,0.f};
#pragma unroll
        for (int d = 0; d < 7; ++d) {
            float w = wv.w[d];
            int off = (r + d) * 64 + c0;
            mx  += w * *(const v4*)&buf[0 * 1408 + off];
            my  += w * *(const v4*)&buf[1 * 1408 + off];
            sxx += w * *(const v4*)&buf[2 * 1408 + off];
            syy += w * *(const v4*)&buf[3 * 1408 + off];
            sxy += w * *(const v4*)&buf[4 * 1408 + off];
        }
        const float C1 = 0.0004f, C2 = 0.0036f, COVN = 49.f / 48.f;
        v4 mxsq = mx * mx;
        v4 mysq = my * my;
        v4 mxy  = mx * my;
        v4 vx   = (sxx - mxsq) * COVN;
        v4 vy   = (syy - mysq) * COVN;
        v4 vxy  = (sxy - mxy)  * COVN;
        v4 num  = (2.f * mxy + C1) * (2.f * vxy + C2);
        v4 den  = (mxsq + mysq + C1) * (vx + vy + C2);
        v4 q;
        q.x = num.x * __builtin_amdgcn_rcpf(den.x);
        q.y = num.y * __builtin_amdgcn_rcpf(den.y);
        q.z = num.z * __builtin_amdgcn_rcpf(den.z);
        q.w = num.w * __builtin_amdgcn_rcpf(den.w);
        float lsum = (q.x + q.y) + (q.z + q.w);

        // block reduction -> per-block partial (no atomic, no init needed)
#pragma unroll
        for (int off = 32; off > 0; off >>= 1)
            lsum += __shfl_down(lsum, off, 64);
        if ((tid & 63) == 0) wsum[tid >> 6] = lsum;
        __syncthreads();
        if (tid == 0) {
            int bid = (blockIdx.z * gridDim.y + blockIdx.y) * gridDim.x + blockIdx.x;
            partial[bid] = (wsum[0] + wsum[1]) + (wsum[2] + wsum[3]);
        }
    }
}

__global__ __launch_bounds__(256) void ssim_finalize(
    const float* __restrict__ partial, float* __restrict__ out)
{
    __shared__ double ws[4];
    const int tid = threadIdx.x;
    double s = 0.0;
    for (int i = tid; i < NBLK; i += 256) s += (double)partial[i];
#pragma unroll
    for (int off = 32; off > 0; off >>= 1)
        s += __shfl_down(s, off, 64);
    if ((tid & 63) == 0) ws[tid >> 6] = s;
    __syncthreads();
    if (tid == 0)
        out[0] = (float)(1.0 - ((ws[0] + ws[1]) + (ws[2] + ws[3])) / NPIX);
}

extern "C" void kernel_launch(void* const* d_in, const int* in_sizes, int n_in,
                              void* d_out, int out_size, void* d_ws, size_t ws_size,
                              hipStream_t stream) {
    const float* X = (const float*)d_in[0];
    const float* Y = (const float*)d_in[1];
    // Rebuild exact 1D Gaussian weights in fp64 (window = outer product).
    W7 wv;
    {
        double g[7], s = 0.0;
        for (int i = 0; i < 7; ++i) {
            double x = (double)(i - 3);
            g[i] = exp(-(x * x) / (2.0 * 1.5 * 1.5));
            s += g[i];
        }
        for (int i = 0; i < 7; ++i) wv.w[i] = (float)(g[i] / s);
    }

    float* partial = (float*)d_ws;   // 6400 floats, fully written each launch

    dim3 grid(WI / TW, HI / TH, NI);   // 5 x 20 x 64 = 6400
    ssim_kernel<<<grid, 256, 0, stream>>>(X, Y, wv, partial);
    ssim_finalize<<<1, 256, 0, stream>>>(partial, (float*)d_out);
}

// Round 3
// 114.553 us; speedup vs baseline: 1.5178x; 1.0660x over previous
//
#include <hip/hip_runtime.h>
#include <math.h>

// SSIM on MI355X, round 3: vertical-first separable conv (sliding window in
// registers, columns = lanes for coalescing), single LDS round-trip for the
// horizontal pass, 64x32 tiles, per-block partials.

#define WI 320
#define HI 320
#define NI 64
#define TW 64
#define TH 32
#define GXD 5                 // WI/TW
#define GYD 10                // HI/TH
#define NBLK (GXD * GYD * NI) // 3200
#define LSTR 72               // vfilt row stride (floats); 288 B, 16B-aligned
#define NPIX ((double)NI * WI * HI)

typedef float v4 __attribute__((ext_vector_type(4)));

struct W7 { float w[7]; };

// Vertical 7-tap for one column task: band (8 output rows), column ci (0..69,
// image col = tx0+ci-3, LDS idx = ci+1). Streams 14 input rows, accumulates
// 5 channels x 8 rows in registers, writes vfilt to LDS.
template <bool INTERIOR>
__device__ __forceinline__ void column_task(
    const float* __restrict__ Xn, const float* __restrict__ Yn,
    const W7& wv, float* __restrict__ vbuf, int tx0, int ty0, int band, int ci)
{
    const int gx  = tx0 + ci - 3;
    const bool xok = (unsigned)gx < (unsigned)WI;
    const int gy0 = ty0 + band * 8 - 3;

    float acc[5][8];
#pragma unroll
    for (int ch = 0; ch < 5; ++ch)
#pragma unroll
        for (int r = 0; r < 8; ++r) acc[ch][r] = 0.f;

#pragma unroll
    for (int j = 0; j < 14; ++j) {
        const int gy = gy0 + j;
        float xv = 0.f, yv = 0.f;
        const bool ok = INTERIOR ? xok : (xok && ((unsigned)gy < (unsigned)HI));
        if (ok) {
            int idx = gy * WI + gx;
            xv = Xn[idx];
            yv = Yn[idx];
        }
        const float pxx = xv * xv, pyy = yv * yv, pxy = xv * yv;
#pragma unroll
        for (int r = 0; r < 8; ++r) {
            const int d = j - r;               // compile-time predicate
            if (d >= 0 && d < 7) {
                const float w = wv.w[d];
                acc[0][r] += w * xv;
                acc[1][r] += w * yv;
                acc[2][r] += w * pxx;
                acc[3][r] += w * pyy;
                acc[4][r] += w * pxy;
            }
        }
    }
#pragma unroll
    for (int ch = 0; ch < 5; ++ch)
#pragma unroll
        for (int r = 0; r < 8; ++r)
            vbuf[ch * (TH * LSTR) + (band * 8 + r) * LSTR + (ci + 1)] = acc[ch][r];
}

__global__ __launch_bounds__(256) void ssim_kernel(
    const float* __restrict__ X, const float* __restrict__ Y,
    W7 wv, float* __restrict__ partial)
{
    __shared__ __align__(16) float vbuf[5 * TH * LSTR];   // 46080 B
    __shared__ float wsum[4];

    const int tid = threadIdx.x;
    const int tx0 = blockIdx.x * TW;
    const int ty0 = blockIdx.y * TH;
    const float* __restrict__ Xn = X + (size_t)blockIdx.z * (WI * HI);
    const float* __restrict__ Yn = Y + (size_t)blockIdx.z * (WI * HI);

    // ---- phase 1: vertical conv. 280 column tasks = 4 bands x 70 cols.
    // Main 256: band = tid>>6 (wave-uniform), ci = tid&63 (coalesced).
    // Extra 24: band = tid/6, ci = 64 + tid%6.
    const bool interior = (blockIdx.y >= 1) && (blockIdx.y <= GYD - 2);
    if (interior) {
        column_task<true>(Xn, Yn, wv, vbuf, tx0, ty0, tid >> 6, tid & 63);
        if (tid < 24) column_task<true>(Xn, Yn, wv, vbuf, tx0, ty0, tid / 6, 64 + tid % 6);
    } else {
        column_task<false>(Xn, Yn, wv, vbuf, tx0, ty0, tid >> 6, tid & 63);
        if (tid < 24) column_task<false>(Xn, Yn, wv, vbuf, tx0, ty0, tid / 6, 64 + tid % 6);
    }
    __syncthreads();

    // ---- phase 2: horizontal 7-tap + SSIM. Thread -> (row, 4 consecutive x).
    // 16 consecutive lanes read 256 contiguous LDS bytes -> conflict-free.
    const float C1 = 0.0004f, C2 = 0.0036f, COVN = 49.f / 48.f;
    const int xg   = (tid & 15) << 2;   // x0: 0,4,...,60
    const int row0 = tid >> 4;          // 0..15

    float lsum = 0.f;
#pragma unroll
    for (int pass = 0; pass < 2; ++pass) {
        const int row = row0 + pass * 16;
        float f[5][12];
#pragma unroll
        for (int ch = 0; ch < 5; ++ch) {
            const v4* p = (const v4*)&vbuf[ch * (TH * LSTR) + row * LSTR + xg];
            v4 a = p[0], b = p[1], c = p[2];
            f[ch][0] = a.x; f[ch][1] = a.y; f[ch][2]  = a.z; f[ch][3]  = a.w;
            f[ch][4] = b.x; f[ch][5] = b.y; f[ch][6]  = b.z; f[ch][7]  = b.w;
            f[ch][8] = c.x; f[ch][9] = c.y; f[ch][10] = c.z; f[ch][11] = c.w;
        }
#pragma unroll
        for (int j = 0; j < 4; ++j) {
            float mx = 0.f, my = 0.f, sxx = 0.f, syy = 0.f, sxy = 0.f;
#pragma unroll
            for (int d = 0; d < 7; ++d) {
                const float w = wv.w[d];
                mx  += w * f[0][j + d + 1];
                my  += w * f[1][j + d + 1];
                sxx += w * f[2][j + d + 1];
                syy += w * f[3][j + d + 1];
                sxy += w * f[4][j + d + 1];
            }
            const float mxsq = mx * mx;
            const float mysq = my * my;
            const float mxy  = mx * my;
            const float vx   = (sxx - mxsq) * COVN;
            const float vy   = (syy - mysq) * COVN;
            const float vxy  = (sxy - mxy)  * COVN;
            const float num  = (2.f * mxy + C1) * (2.f * vxy + C2);
            const float den  = (mxsq + mysq + C1) * (vx + vy + C2);
            lsum += num * __builtin_amdgcn_rcpf(den);
        }
    }

    // ---- block reduction -> per-block partial ----
#pragma unroll
    for (int off = 32; off > 0; off >>= 1)
        lsum += __shfl_down(lsum, off, 64);
    if ((tid & 63) == 0) wsum[tid >> 6] = lsum;
    __syncthreads();
    if (tid == 0) {
        int bid = (blockIdx.z * GYD + blockIdx.y) * GXD + blockIdx.x;
        partial[bid] = (wsum[0] + wsum[1]) + (wsum[2] + wsum[3]);
    }
}

__global__ __launch_bounds__(256) void ssim_finalize(
    const float* __restrict__ partial, float* __restrict__ out)
{
    __shared__ double ws[4];
    const int tid = threadIdx.x;
    double s = 0.0;
    for (int i = tid; i < NBLK; i += 256) s += (double)partial[i];
#pragma unroll
    for (int off = 32; off > 0; off >>= 1)
        s += __shfl_down(s, off, 64);
    if ((tid & 63) == 0) ws[tid >> 6] = s;
    __syncthreads();
    if (tid == 0)
        out[0] = (float)(1.0 - ((ws[0] + ws[1]) + (ws[2] + ws[3])) / NPIX);
}

extern "C" void kernel_launch(void* const* d_in, const int* in_sizes, int n_in,
                              void* d_out, int out_size, void* d_ws, size_t ws_size,
                              hipStream_t stream) {
    const float* X = (const float*)d_in[0];
    const float* Y = (const float*)d_in[1];
    // Exact 1D Gaussian weights in fp64 (7x7 window = outer product).
    W7 wv;
    {
        double g[7], s = 0.0;
        for (int i = 0; i < 7; ++i) {
            double x = (double)(i - 3);
            g[i] = exp(-(x * x) / (2.0 * 1.5 * 1.5));
            s += g[i];
        }
        for (int i = 0; i < 7; ++i) wv.w[i] = (float)(g[i] / s);
    }

    float* partial = (float*)d_ws;   // 3200 floats, fully written every launch

    dim3 grid(GXD, GYD, NI);
    ssim_kernel<<<grid, 256, 0, stream>>>(X, Y, wv, partial);
    ssim_finalize<<<1, 256, 0, stream>>>(partial, (float*)d_out);
}